// Round 10
// baseline (213.050 us; speedup 1.0000x reference)
//
#include <hip/hip_runtime.h>
#include <cstddef>

#define H_ 128
#define W_ 128
#define HW_ 16384
#define C_ 64
#define B_ 8
#define EPS_ 1e-5f

#define KSLOTS 19   // deform GEMM k-slots, k = kk*68 + c, k < 608
#define ROWS 616    // sAb row stride (shorts)
#define TSTR 72     // tileTb row stride (shorts): 36 dwords -> bank step 4 (2-way)

typedef __attribute__((ext_vector_type(8))) short bf16x8;
typedef __attribute__((ext_vector_type(4))) float f32x4;
typedef unsigned short ushortx;

__device__ __forceinline__ unsigned short f2bf(float f) {
  unsigned u = __float_as_uint(f);
  unsigned r = (u + 0x7FFFu + ((u >> 16) & 1u)) >> 16;
  return (unsigned short)r;
}
__device__ __forceinline__ float bfl(unsigned short v) {
  return __uint_as_float(((unsigned)v) << 16);
}

// ---------------- prep: pack ALL GEMM weights into MFMA fragment order ------
// wf2: deform (k=kk*68+c, 19 slots). offwp: offset conv (slot=kk*2+s, k=c).
// w1p/w2p: 1x1 convs (k=c, 2 slots), BN folded into w1p. b1f folded bias.
__global__ __launch_bounds__(256) void prep_kernel(
    const float* __restrict__ dw, const float* __restrict__ offw,
    const float* __restrict__ w1, const float* __restrict__ b1,
    const float* __restrict__ gamma, const float* __restrict__ beta,
    const float* __restrict__ rmean, const float* __restrict__ rvar,
    const float* __restrict__ w2,
    unsigned short* __restrict__ wf2, unsigned short* __restrict__ offwp,
    unsigned short* __restrict__ w1p, unsigned short* __restrict__ w2p,
    float* __restrict__ b1f) {
  int i = blockIdx.x * 256 + threadIdx.x;
  if (i < 38912) {  // 19 sg * 4 og * 64 l * 8 j
    int j = i & 7, l = (i >> 3) & 63, og = (i >> 9) & 3, sg = i >> 11;
    int o = og * 16 + (l & 15);
    int k = sg * 32 + ((l >> 4) << 3) + j;  // 0..607
    int kk = k / 68, c = k - kk * 68;
    float v = (c < 64) ? dw[o * 576 + c * 9 + kk] : 0.f;
    wf2[i] = f2bf(v);
  } else if (i < 38912 + 18432) {  // 18 slot * 2 og * 64 l * 8 j
    int j2 = i - 38912;
    int j = j2 & 7, l = (j2 >> 3) & 63, og = (j2 >> 9) & 1, slot = j2 >> 10;
    int kk = slot >> 1, s = slot & 1;
    int oc = og * 16 + (l & 15);
    int c = s * 32 + ((l >> 4) << 3) + j;
    float v = (oc < 18) ? offw[oc * 576 + c * 9 + kk] : 0.f;
    offwp[j2] = f2bf(v);
  } else if (i < 38912 + 18432 + 4096) {
    int j2 = i - 38912 - 18432;
    int j = j2 & 7, l = (j2 >> 3) & 63, og = (j2 >> 9) & 3, sg = j2 >> 11;
    int o = og * 16 + (l & 15);
    int c = sg * 32 + ((l >> 4) << 3) + j;
    float inv = gamma[o] * rsqrtf(rvar[o] + EPS_);
    w1p[j2] = f2bf(w1[o * 64 + c] * inv);
  } else if (i < 38912 + 18432 + 8192) {
    int j2 = i - 38912 - 18432 - 4096;
    int j = j2 & 7, l = (j2 >> 3) & 63, og = (j2 >> 9) & 3, sg = j2 >> 11;
    int o = og * 16 + (l & 15);
    int c = sg * 32 + ((l >> 4) << 3) + j;
    w2p[j2] = f2bf(w2[o * 64 + c]);
  } else if (i < 38912 + 18432 + 8192 + 64) {
    int o = i - 38912 - 18432 - 8192;
    float inv = gamma[o] * rsqrtf(rvar[o] + EPS_);
    b1f[o] = b1[o] * inv + beta[o] - rmean[o] * inv;
  }
}

// ---------------- avg pool 3x3, vectorized: 4 px / thread ----------------
__global__ __launch_bounds__(256) void avgpool_kernel(const float* __restrict__ xin,
                                                      float* __restrict__ p) {
  int i = blockIdx.x * 256 + threadIdx.x;
  int gi = i * 4;
  int bc = gi >> 14;
  int yx = gi & 16383;
  int y = yx >> 7, x0 = yx & 127;
  const float* q = xin + (size_t)bc * HW_;
  float s0 = 0.f, s1 = 0.f, s2 = 0.f, s3 = 0.f;
#pragma unroll
  for (int dy = -1; dy <= 1; ++dy) {
    int yy = y + dy;
    if ((unsigned)yy < 128u) {
      const float* row = q + yy * W_;
      float4 m = *(const float4*)(row + x0);
      float lft = (x0 > 0) ? row[x0 - 1] : 0.f;
      float rgt = (x0 < 124) ? row[x0 + 4] : 0.f;
      s0 += lft + m.x + m.y;
      s1 += m.x + m.y + m.z;
      s2 += m.y + m.z + m.w;
      s3 += m.z + m.w + rgt;
    }
  }
  *(float4*)(p + gi) = make_float4(s0 * (1.f / 9.f), s1 * (1.f / 9.f),
                                   s2 * (1.f / 9.f), s3 * (1.f / 9.f));
}

// ---- fully fused: offconv(MFMA) + deform sample + deform GEMM + tail -------
// Block: 256 thr (4 waves), 16 pixels. bf16 p-tile [100 rc][72] with
// UNCLAMPED origin (ty=y-2,tx=x0-2) and zero-fill = conv zero-padding.
// Offconv A-frags read in-place at row base_kk+l15 (no im2col). Sampling is
// wave-uniform jobs (lane = channel, conflict-free stride-1 reads).
__global__ __launch_bounds__(256, 3) void deform_kernel(
    const float* __restrict__ p, const float* __restrict__ offb,
    const unsigned short* __restrict__ wf2, const unsigned short* __restrict__ offwp,
    const unsigned short* __restrict__ w1p, const unsigned short* __restrict__ w2p,
    const float* __restrict__ db, const float* __restrict__ b1f,
    const float* __restrict__ b2, const float* __restrict__ xin,
    float* __restrict__ out) {
  __shared__ __align__(16) unsigned short tileTb[100 * TSTR];  // 14400 B
  __shared__ __align__(16) unsigned short sAb[16 * ROWS];      // 19712 B
  __shared__ float offT[16 * 20];                              // 1280 B
  __shared__ float4 cw4[144];
  __shared__ int4 ci4[144];
  __shared__ uchar4 rel4[144];
  __shared__ __align__(16) unsigned short rTb[16 * 72];
  __shared__ __align__(16) unsigned short hTb[16 * 72];
  __shared__ int wOK[4];
  int t = threadIdx.x;
  int lane = t & 63, wv = t >> 6;
  int l15 = lane & 15, lp = lane >> 4;
  int pix0 = blockIdx.x * 16;
  int b = pix0 >> 14;
  int yx0 = pix0 & 16383;
  int y = yx0 >> 7, x0 = yx0 & 127;
  int ty = y - 2, tx = x0 - 2;  // UNclamped
  const float* pb = p + (size_t)b * C_ * HW_;
  int o_me = wv * 16 + l15;
  int px0 = lp * 4;
  const float4 xv = *(const float4*)(xin + (size_t)(b * C_ + o_me) * HW_ + yx0 + px0);

  // ---- Phase 0: stage bf16 tile (zero-filled OOB) + zero c-pad ----
#pragma unroll
  for (int it = 0; it < 25; ++it) {
    int idx = it * 256 + t;  // c = idx/100, rc = idx%100
    int c = idx / 100;
    int rc = idx - c * 100;
    int r = rc / 20, cx = rc - r * 20;
    int iy = ty + r, ix = tx + cx;
    bool v = ((unsigned)iy < 128u) && ((unsigned)ix < 128u);
    float val = v ? pb[(size_t)c * HW_ + iy * W_ + ix] : 0.f;
    tileTb[rc * TSTR + c] = v ? f2bf(val) : (unsigned short)0;
  }
  if (t < 200) {  // zero c = 64..71 on all 100 rows
    *(uint2*)(tileTb + (t >> 1) * TSTR + 64 + (t & 1) * 4) = make_uint2(0u, 0u);
  }
  __syncthreads();

  // ---- Phase 1: offset conv via MFMA (waves 0,1), D -> offT ----
  if (wv < 2) {
    int oc = wv * 16 + l15;
    float bo = offb[min(oc, 17)];
    f32x4 aco = (f32x4){bo, bo, bo, bo};
    const bf16x8* ofp = (const bf16x8*)offwp;
#pragma unroll
    for (int kk = 0; kk < 9; ++kk) {
      int base = (kk / 3 + 1) * 20 + (kk % 3 + 1);
#pragma unroll
      for (int s = 0; s < 2; ++s) {
        bf16x8 a = *(const bf16x8*)(tileTb + (base + l15) * TSTR + s * 32 + lp * 8);
        bf16x8 bw = ofp[((kk * 2 + s) * 2 + wv) * 64 + lane];
        aco = __builtin_amdgcn_mfma_f32_16x16x32_bf16(a, bw, aco, 0, 0, 0);
      }
    }
    if (oc < 18) {
#pragma unroll
      for (int j = 0; j < 4; ++j) offT[(px0 + j) * 20 + oc] = aco[j];
    }
  }
  __syncthreads();

  // ---- Phase 2: bilinear params (R9-identical math; offsets from offT) ----
  bool ok = true;
  if (t < 144) {
    int pixl = t & 15, kk = t >> 4;
    int xx = x0 + pixl;
    float offy = offT[pixl * 20 + 2 * kk];
    float offx = offT[pixl * 20 + 2 * kk + 1];
    float sy = (float)(y + (kk / 3) - 1) + offy;
    float sx = (float)(xx + (kk % 3) - 1) + offx;
    float fy = floorf(sy), fx = floorf(sx);
    float wy = sy - fy, wx = sx - fx;
    int iy = (int)fy, ix = (int)fx;
    float w[4];
    int id[4];
    unsigned rel[4];
#pragma unroll
    for (int j = 0; j < 4; ++j) {
      int dy = j >> 1, dx = j & 1;
      int yc = iy + dy, xc = ix + dx;
      bool v = ((unsigned)yc < 128u) && ((unsigned)xc < 128u);
      int ycc = min(max(yc, 0), 127), xcc = min(max(xc, 0), 127);
      float wgt = (dy ? wy : 1.f - wy) * (dx ? wx : 1.f - wx);
      w[j] = v ? wgt : 0.f;
      id[j] = ycc * W_ + xcc;
      bool in_tile = (ycc >= ty) && (ycc <= ty + 4) && (xcc >= tx) && (xcc <= tx + 19);
      ok = ok && ((w[j] == 0.f) || in_tile);
      int ry = min(max(ycc - ty, 0), 4);
      int rx = min(max(xcc - tx, 0), 19);
      rel[j] = (unsigned)(ry * 20 + rx);
    }
    cw4[t] = make_float4(w[0], w[1], w[2], w[3]);
    ci4[t] = make_int4(id[0], id[1], id[2], id[3]);
    rel4[t] = make_uchar4((unsigned char)rel[0], (unsigned char)rel[1],
                          (unsigned char)rel[2], (unsigned char)rel[3]);
  }
  {
    unsigned long long m = __ballot(ok);
    if (lane == 0) wOK[wv] = (m == ~0ull) ? 1 : 0;
  }
  __syncthreads();

  bool fast = wOK[0] && wOK[1] && wOK[2] && wOK[3];

  // ---- Phase 3: sampling. Wave-uniform job (pixl,kk); lane = channel ----
  if (fast) {
#pragma unroll 4
    for (int j = 0; j < 36; ++j) {
      int jo = j * 4 + wv;  // 0..143
      int pixl = jo & 15, kk = jo >> 4;
      float4 w = cw4[jo];
      uchar4 rl = rel4[jo];
      float v0 = bfl(tileTb[(int)rl.x * TSTR + lane]);
      float v1 = bfl(tileTb[(int)rl.y * TSTR + lane]);
      float v2 = bfl(tileTb[(int)rl.z * TSTR + lane]);
      float v3 = bfl(tileTb[(int)rl.w * TSTR + lane]);
      float val = w.x * v0 + w.y * v1 + w.z * v2 + w.w * v3;
      unsigned short* wr = sAb + pixl * ROWS + kk * 68;
      wr[lane] = f2bf(val);
      if (lane < 4) wr[64 + lane] = 0;
    }
  } else {
    if (t < 144) {
      int pixl = t & 15, kk = t >> 4;
      float4 w = cw4[t];
      int4 id = ci4[t];
      unsigned short* wr = sAb + pixl * ROWS + kk * 68;
#pragma unroll 4
      for (int c = 0; c < 64; ++c) {
        const float* pc = pb + (size_t)c * HW_;
        float v = w.x * pc[id.x] + w.y * pc[id.y] + w.z * pc[id.z] + w.w * pc[id.w];
        wr[c] = f2bf(v);
      }
      *(uint2*)(wr + 64) = make_uint2(0u, 0u);
    }
  }
  __syncthreads();

  // ---- Phase 4: deform GEMM (19 slots; verified A/B pairing + D layout) ----
  f32x4 acc;
  {
    float d = db[o_me];
    acc = (f32x4){d, d, d, d};
  }
  const unsigned short* arow = sAb + l15 * ROWS + (lp << 3);
  const bf16x8* wfp = (const bf16x8*)wf2;
#pragma unroll
  for (int s = 0; s < KSLOTS; ++s) {
    bf16x8 a = *(const bf16x8*)(arow + s * 32);
    bf16x8 bw = wfp[(s * 4 + wv) * 64 + lane];
    acc = __builtin_amdgcn_mfma_f32_16x16x32_bf16(a, bw, acc, 0, 0, 0);
  }

  // ---- r -> bf16 LDS [px][o] ----
#pragma unroll
  for (int j = 0; j < 4; ++j) {
    rTb[(px0 + j) * 72 + o_me] = f2bf(acc[j]);
  }
  __syncthreads();

  // ---- conv1 + BN + ReLU + residual ----
  f32x4 acc1;
  {
    float bb = b1f[o_me];
    acc1 = (f32x4){bb, bb, bb, bb};
  }
  const unsigned short* arow1 = rTb + l15 * 72 + (lp << 3);
  const bf16x8* w1f8 = (const bf16x8*)w1p;
#pragma unroll
  for (int s = 0; s < 2; ++s) {
    bf16x8 a = *(const bf16x8*)(arow1 + s * 32);
    bf16x8 bw = w1f8[(s * 4 + wv) * 64 + lane];
    acc1 = __builtin_amdgcn_mfma_f32_16x16x32_bf16(a, bw, acc1, 0, 0, 0);
  }
  float h0 = fmaxf(acc1[0], 0.f) + xv.x;
  float h1 = fmaxf(acc1[1], 0.f) + xv.y;
  float h2 = fmaxf(acc1[2], 0.f) + xv.z;
  float h3 = fmaxf(acc1[3], 0.f) + xv.w;
  hTb[(px0 + 0) * 72 + o_me] = f2bf(h0);
  hTb[(px0 + 1) * 72 + o_me] = f2bf(h1);
  hTb[(px0 + 2) * 72 + o_me] = f2bf(h2);
  hTb[(px0 + 3) * 72 + o_me] = f2bf(h3);
  __syncthreads();

  // ---- conv2 ----
  f32x4 acc2;
  {
    float bo = b2[o_me];
    acc2 = (f32x4){bo, bo, bo, bo};
  }
  const unsigned short* arow2 = hTb + l15 * 72 + (lp << 3);
  const bf16x8* w2f8 = (const bf16x8*)w2p;
#pragma unroll
  for (int s = 0; s < 2; ++s) {
    bf16x8 a = *(const bf16x8*)(arow2 + s * 32);
    bf16x8 bw = w2f8[(s * 4 + wv) * 64 + lane];
    acc2 = __builtin_amdgcn_mfma_f32_16x16x32_bf16(a, bw, acc2, 0, 0, 0);
  }
  *(float4*)(out + (size_t)(b * C_ + o_me) * HW_ + yx0 + px0) =
      make_float4(acc2[0], acc2[1], acc2[2], acc2[3]);
}

extern "C" void kernel_launch(void* const* d_in, const int* in_sizes, int n_in,
                              void* d_out, int out_size, void* d_ws, size_t ws_size,
                              hipStream_t stream) {
  const float* x = (const float*)d_in[0];
  const float* offw = (const float*)d_in[1];
  const float* offb = (const float*)d_in[2];
  const float* dw = (const float*)d_in[3];
  const float* db = (const float*)d_in[4];
  const float* w1 = (const float*)d_in[5];
  const float* b1 = (const float*)d_in[6];
  const float* gamma = (const float*)d_in[7];
  const float* beta = (const float*)d_in[8];
  const float* rmean = (const float*)d_in[9];
  const float* rvar = (const float*)d_in[10];
  const float* w2 = (const float*)d_in[11];
  const float* b2 = (const float*)d_in[12];
  float* out = (float*)d_out;

  float* ws = (float*)d_ws;
  float* p = ws;  // 8388608 f
  unsigned short* wf2 = (unsigned short*)(p + 8388608);  // 38912 bf16
  unsigned short* offwp = wf2 + 38912;                   // 18432 bf16
  unsigned short* w1p = offwp + 18432;                   // 4096 bf16
  unsigned short* w2p = w1p + 4096;                      // 4096 bf16
  float* b1f = (float*)(w2p + 4096);                     // 64 f

  prep_kernel<<<257, 256, 0, stream>>>(dw, offw, w1, b1, gamma, beta, rmean,
                                       rvar, w2, wf2, offwp, w1p, w2p, b1f);
  avgpool_kernel<<<8192, 256, 0, stream>>>(x, p);
  deform_kernel<<<8192, 256, 0, stream>>>(p, offb, wf2, offwp, w1p, w2p, db,
                                          b1f, b2, x, out);
}

// Round 11
// 159.252 us; speedup vs baseline: 1.3378x; 1.3378x over previous
//
#include <hip/hip_runtime.h>
#include <cstddef>

#define H_ 128
#define W_ 128
#define HW_ 16384
#define C_ 64
#define B_ 8
#define EPS_ 1e-5f

#define KSLOTS 19   // deform GEMM k-slots, k = kk*68 + c, k < 608
#define ROWS 616    // sAb row stride (shorts)
#define TSTR 72     // deform tile row stride (shorts), 144 B (16B-aligned)
#define OTSTR 72    // offconv tile row stride (shorts)

typedef __attribute__((ext_vector_type(8))) short bf16x8;
typedef __attribute__((ext_vector_type(4))) float f32x4;

__device__ __forceinline__ unsigned short f2bf(float f) {
  unsigned u = __float_as_uint(f);
  unsigned r = (u + 0x7FFFu + ((u >> 16) & 1u)) >> 16;
  return (unsigned short)r;
}
__device__ __forceinline__ float bfl(unsigned short v) {
  return __uint_as_float(((unsigned)v) << 16);
}

// ---------------- prep: pack ALL GEMM weights into MFMA fragment order ------
// (identical to R10's validated prep)
__global__ __launch_bounds__(256) void prep_kernel(
    const float* __restrict__ dw, const float* __restrict__ offw,
    const float* __restrict__ w1, const float* __restrict__ b1,
    const float* __restrict__ gamma, const float* __restrict__ beta,
    const float* __restrict__ rmean, const float* __restrict__ rvar,
    const float* __restrict__ w2,
    unsigned short* __restrict__ wf2, unsigned short* __restrict__ offwp,
    unsigned short* __restrict__ w1p, unsigned short* __restrict__ w2p,
    float* __restrict__ b1f) {
  int i = blockIdx.x * 256 + threadIdx.x;
  if (i < 38912) {  // deform: 19 sg * 4 og * 64 l * 8 j
    int j = i & 7, l = (i >> 3) & 63, og = (i >> 9) & 3, sg = i >> 11;
    int o = og * 16 + (l & 15);
    int k = sg * 32 + ((l >> 4) << 3) + j;  // 0..607
    int kk = k / 68, c = k - kk * 68;
    float v = (c < 64) ? dw[o * 576 + c * 9 + kk] : 0.f;
    wf2[i] = f2bf(v);
  } else if (i < 38912 + 18432) {  // offconv: 18 slot * 2 og * 64 l * 8 j
    int j2 = i - 38912;
    int j = j2 & 7, l = (j2 >> 3) & 63, og = (j2 >> 9) & 1, slot = j2 >> 10;
    int kk = slot >> 1, s = slot & 1;
    int oc = og * 16 + (l & 15);
    int c = s * 32 + ((l >> 4) << 3) + j;
    float v = (oc < 18) ? offw[oc * 576 + c * 9 + kk] : 0.f;
    offwp[j2] = f2bf(v);
  } else if (i < 38912 + 18432 + 4096) {
    int j2 = i - 38912 - 18432;
    int j = j2 & 7, l = (j2 >> 3) & 63, og = (j2 >> 9) & 3, sg = j2 >> 11;
    int o = og * 16 + (l & 15);
    int c = sg * 32 + ((l >> 4) << 3) + j;
    float inv = gamma[o] * rsqrtf(rvar[o] + EPS_);
    w1p[j2] = f2bf(w1[o * 64 + c] * inv);
  } else if (i < 38912 + 18432 + 8192) {
    int j2 = i - 38912 - 18432 - 4096;
    int j = j2 & 7, l = (j2 >> 3) & 63, og = (j2 >> 9) & 3, sg = j2 >> 11;
    int o = og * 16 + (l & 15);
    int c = sg * 32 + ((l >> 4) << 3) + j;
    w2p[j2] = f2bf(w2[o * 64 + c]);
  } else if (i < 38912 + 18432 + 8192 + 64) {
    int o = i - 38912 - 18432 - 8192;
    float inv = gamma[o] * rsqrtf(rvar[o] + EPS_);
    b1f[o] = b1[o] * inv + beta[o] - rmean[o] * inv;
  }
}

// ---------------- avg pool 3x3, vectorized: 4 px / thread ----------------
__global__ __launch_bounds__(256) void avgpool_kernel(const float* __restrict__ xin,
                                                      float* __restrict__ p) {
  int i = blockIdx.x * 256 + threadIdx.x;
  int gi = i * 4;
  int bc = gi >> 14;
  int yx = gi & 16383;
  int y = yx >> 7, x0 = yx & 127;
  const float* q = xin + (size_t)bc * HW_;
  float s0 = 0.f, s1 = 0.f, s2 = 0.f, s3 = 0.f;
#pragma unroll
  for (int dy = -1; dy <= 1; ++dy) {
    int yy = y + dy;
    if ((unsigned)yy < 128u) {
      const float* row = q + yy * W_;
      float4 m = *(const float4*)(row + x0);
      float lft = (x0 > 0) ? row[x0 - 1] : 0.f;
      float rgt = (x0 < 124) ? row[x0 + 4] : 0.f;
      s0 += lft + m.x + m.y;
      s1 += m.x + m.y + m.z;
      s2 += m.y + m.z + m.w;
      s3 += m.z + m.w + rgt;
    }
  }
  *(float4*)(p + gi) = make_float4(s0 * (1.f / 9.f), s1 * (1.f / 9.f),
                                   s2 * (1.f / 9.f), s3 * (1.f / 9.f));
}

// ---------------- offset conv via MFMA: 64 px/block, all 4 waves busy -------
// Tile: rows y-1..y+1 (zero-filled OOB = conv padding), cols x0-1..x0+64.
// A-frags read in place (im2col-free); B = offwp (R10-validated pairing).
__global__ __launch_bounds__(256, 4) void offconv_kernel(
    const float* __restrict__ p, const unsigned short* __restrict__ offwp,
    const float* __restrict__ offb, float* __restrict__ off) {
  __shared__ __align__(16) unsigned short tile[198 * OTSTR];  // 28512 B
  __shared__ float offT[18 * 64];                             // 4608 B
  int t = threadIdx.x;
  int lane = t & 63, wv = t >> 6;
  int l15 = lane & 15, lp = lane >> 4;
  int blk = blockIdx.x;
  int half = blk & 1;
  int row = blk >> 1;            // 0..1023
  int b = row >> 7, y = row & 127;
  int x0 = half * 64;
  const float* pb = p + (size_t)b * C_ * HW_;

  // stage tile: c = idx/198, rc = idx%198 (r = rc/66, cx = rc%66)
#pragma unroll
  for (int it = 0; it < 50; ++it) {
    int idx = it * 256 + t;
    if (idx < 12672) {
      int c = idx / 198;
      int rc = idx - c * 198;
      int r = rc / 66, cx = rc - r * 66;
      int iy = y - 1 + r, ix = x0 - 1 + cx;
      bool v = ((unsigned)iy < 128u) && ((unsigned)ix < 128u);
      float val = v ? pb[(size_t)c * HW_ + iy * W_ + ix] : 0.f;
      tile[rc * OTSTR + c] = v ? f2bf(val) : (unsigned short)0;
    }
  }
  if (t < 198) {  // zero c = 64..71
    *(uint2*)(tile + t * OTSTR + 64) = make_uint2(0u, 0u);
    *(uint2*)(tile + t * OTSTR + 68) = make_uint2(0u, 0u);
  }
  __syncthreads();

  // MFMA: wave wv -> og = wv&1, pixel-tiles pt = (wv>>1) and (wv>>1)+2
  int og = wv & 1;
  int oc = og * 16 + l15;
  float bo = offb[min(oc, 17)];
  const bf16x8* ofp = (const bf16x8*)offwp;
#pragma unroll
  for (int pti = 0; pti < 2; ++pti) {
    int pt = (wv >> 1) + pti * 2;
    f32x4 aco = (f32x4){bo, bo, bo, bo};
#pragma unroll
    for (int kk = 0; kk < 9; ++kk) {
      int rowb = (kk / 3) * 66 + (kk % 3) + pt * 16 + l15;
#pragma unroll
      for (int s = 0; s < 2; ++s) {
        bf16x8 a = *(const bf16x8*)(tile + rowb * OTSTR + s * 32 + lp * 8);
        bf16x8 bw = ofp[((kk * 2 + s) * 2 + og) * 64 + lane];
        aco = __builtin_amdgcn_mfma_f32_16x16x32_bf16(a, bw, aco, 0, 0, 0);
      }
    }
    if (oc < 18) {
#pragma unroll
      for (int j = 0; j < 4; ++j) offT[oc * 64 + pt * 16 + lp * 4 + j] = aco[j];
    }
  }
  __syncthreads();

  // coalesced store: off[(b*18+oc)*HW + y*W + x0 + px]
#pragma unroll
  for (int it = 0; it < 5; ++it) {
    int idx = it * 256 + t;
    if (idx < 1152) {
      int oc2 = idx >> 6, px = idx & 63;
      off[(size_t)(b * 18 + oc2) * HW_ + y * W_ + x0 + px] = offT[idx];
    }
  }
}

// ---------------- deform (R9 structure, bf16 tile) + fused tail -------------
__global__ __launch_bounds__(256, 4) void deform_kernel(
    const float* __restrict__ p, const float* __restrict__ off,
    const unsigned short* __restrict__ wf2, const unsigned short* __restrict__ w1p,
    const unsigned short* __restrict__ w2p, const float* __restrict__ db,
    const float* __restrict__ b1f, const float* __restrict__ b2,
    const float* __restrict__ xin, float* __restrict__ out) {
  __shared__ __align__(16) unsigned short tileTb[100 * TSTR];  // 14400 B
  __shared__ __align__(16) unsigned short sAb[16 * ROWS];      // 19712 B
  __shared__ __align__(16) unsigned short rTb[16 * 72];        // 2304 B
  __shared__ __align__(16) unsigned short hTb[16 * 72];        // 2304 B
  __shared__ int wOK[4];
  int t = threadIdx.x;
  int lane = t & 63, wv = t >> 6;
  int l15 = lane & 15, lp = lane >> 4;
  int pix0 = blockIdx.x * 16;
  int b = pix0 >> 14;
  int yx0 = pix0 & 16383;
  int y = yx0 >> 7, x0 = yx0 & 127;
  int ty = min(max(y - 2, 0), 123);
  int tx = min(max(x0 - 2, 0), 108);
  const float* pb = p + (size_t)b * C_ * HW_;

  int o_me = wv * 16 + l15;
  int px0 = lp * 4;
  const float4 xv = *(const float4*)(xin + (size_t)(b * C_ + o_me) * HW_ + yx0 + px0);

  // ---- bilinear params in registers; thread (pixl = t&15, kk = t>>4) ----
  bool ok = true;
  float w0 = 0.f, w1_ = 0.f, w2_ = 0.f, w3_ = 0.f;
  int rc0 = 0, rc1 = 0, rc2 = 0, rc3 = 0;
  int i0 = 0, i1 = 0, i2 = 0, i3 = 0;
  int pixl = t & 15, kk = t >> 4;
  bool active = (t < 144);
  if (active) {
    int xx = x0 + pixl;
    const float* ob = off + (size_t)(b * 18 + kk * 2) * HW_ + y * W_ + xx;
    float offy = ob[0];
    float offx = ob[HW_];
    float sy = (float)(y + (kk / 3) - 1) + offy;
    float sx = (float)(xx + (kk % 3) - 1) + offx;
    float fy = floorf(sy), fx = floorf(sx);
    float wy = sy - fy, wx = sx - fx;
    int iy = (int)fy, ix = (int)fx;
    float w[4];
    int id[4], rc[4];
#pragma unroll
    for (int j = 0; j < 4; ++j) {
      int dy = j >> 1, dx = j & 1;
      int yc = iy + dy, xc = ix + dx;
      bool v = ((unsigned)yc < 128u) && ((unsigned)xc < 128u);
      int ycc = min(max(yc, 0), 127), xcc = min(max(xc, 0), 127);
      float wgt = (dy ? wy : 1.f - wy) * (dx ? wx : 1.f - wx);
      w[j] = v ? wgt : 0.f;
      id[j] = ycc * W_ + xcc;
      bool in_tile = (ycc >= ty) && (ycc <= ty + 4) && (xcc >= tx) && (xcc <= tx + 19);
      ok = ok && ((w[j] == 0.f) || in_tile);
      int ry = min(max(ycc - ty, 0), 4);
      int rx = min(max(xcc - tx, 0), 19);
      rc[j] = ry * 20 + rx;
    }
    w0 = w[0]; w1_ = w[1]; w2_ = w[2]; w3_ = w[3];
    rc0 = rc[0]; rc1 = rc[1]; rc2 = rc[2]; rc3 = rc[3];
    i0 = id[0]; i1 = id[1]; i2 = id[2]; i3 = id[3];
  }
  {
    unsigned long long m = __ballot(ok);
    if (lane == 0) wOK[wv] = (m == ~0ull) ? 1 : 0;
  }

  // ---- stage bf16 p-tile [rc][c] (clamped origin -> always in-bounds) ----
#pragma unroll
  for (int it = 0; it < 25; ++it) {
    int idx = it * 256 + t;  // c = idx/100, rc = idx%100
    int c = idx / 100;
    int rc = idx - c * 100;
    int r = rc / 20, cx = rc - r * 20;
    tileTb[rc * TSTR + c] = f2bf(pb[(size_t)c * HW_ + (ty + r) * W_ + tx + cx]);
  }
  if (active) {  // zero own k-pad strip (c = 64..67)
    *(uint2*)(sAb + pixl * ROWS + kk * 68 + 64) = make_uint2(0u, 0u);
  }
  __syncthreads();

  bool fast = wOK[0] && wOK[1] && wOK[2] && wOK[3];

  // ---- sampling: thread owns (pixl,kk); bf16x8 corner reads ----
  if (active) {
    unsigned short* wr = sAb + pixl * ROWS + kk * 68;
    if (fast) {
      const unsigned short* c0p = tileTb + rc0 * TSTR;
      const unsigned short* c1p = tileTb + rc1 * TSTR;
      const unsigned short* c2p = tileTb + rc2 * TSTR;
      const unsigned short* c3p = tileTb + rc3 * TSTR;
#pragma unroll
      for (int c0 = 0; c0 < 64; c0 += 8) {
        bf16x8 v0 = *(const bf16x8*)(c0p + c0);
        bf16x8 v1 = *(const bf16x8*)(c1p + c0);
        bf16x8 v2 = *(const bf16x8*)(c2p + c0);
        bf16x8 v3 = *(const bf16x8*)(c3p + c0);
        unsigned dws[4];
#pragma unroll
        for (int e = 0; e < 8; e += 2) {
          float lo = w0 * bfl((unsigned short)v0[e]) + w1_ * bfl((unsigned short)v1[e]) +
                     w2_ * bfl((unsigned short)v2[e]) + w3_ * bfl((unsigned short)v3[e]);
          float hi = w0 * bfl((unsigned short)v0[e + 1]) + w1_ * bfl((unsigned short)v1[e + 1]) +
                     w2_ * bfl((unsigned short)v2[e + 1]) + w3_ * bfl((unsigned short)v3[e + 1]);
          dws[e >> 1] = (unsigned)f2bf(lo) | ((unsigned)f2bf(hi) << 16);
        }
        *(uint2*)(wr + c0) = make_uint2(dws[0], dws[1]);
        *(uint2*)(wr + c0 + 4) = make_uint2(dws[2], dws[3]);
      }
    } else {
#pragma unroll 4
      for (int c = 0; c < 64; ++c) {
        const float* pc = pb + (size_t)c * HW_;
        float v = w0 * pc[i0] + w1_ * pc[i1] + w2_ * pc[i2] + w3_ * pc[i3];
        wr[c] = f2bf(v);
      }
    }
  }
  __syncthreads();

  // ---- deform GEMM: 19 slots (verified A/B pairing + D layout) ----
  f32x4 acc;
  {
    float d = db[o_me];
    acc = (f32x4){d, d, d, d};
  }
  const unsigned short* arow = sAb + l15 * ROWS + (lp << 3);
  const bf16x8* wfp = (const bf16x8*)wf2;
#pragma unroll
  for (int s = 0; s < KSLOTS; ++s) {
    bf16x8 a = *(const bf16x8*)(arow + s * 32);
    bf16x8 bw = wfp[(s * 4 + wv) * 64 + lane];
    acc = __builtin_amdgcn_mfma_f32_16x16x32_bf16(a, bw, acc, 0, 0, 0);
  }

  // ---- r -> bf16 LDS [px][o] ----
#pragma unroll
  for (int j = 0; j < 4; ++j) {
    rTb[(px0 + j) * 72 + o_me] = f2bf(acc[j]);
  }
  __syncthreads();

  // ---- conv1 + BN + ReLU + residual ----
  f32x4 acc1;
  {
    float bb = b1f[o_me];
    acc1 = (f32x4){bb, bb, bb, bb};
  }
  const unsigned short* arow1 = rTb + l15 * 72 + (lp << 3);
  const bf16x8* w1f8 = (const bf16x8*)w1p;
#pragma unroll
  for (int s = 0; s < 2; ++s) {
    bf16x8 a = *(const bf16x8*)(arow1 + s * 32);
    bf16x8 bw = w1f8[(s * 4 + wv) * 64 + lane];
    acc1 = __builtin_amdgcn_mfma_f32_16x16x32_bf16(a, bw, acc1, 0, 0, 0);
  }
  float h0 = fmaxf(acc1[0], 0.f) + xv.x;
  float h1 = fmaxf(acc1[1], 0.f) + xv.y;
  float h2 = fmaxf(acc1[2], 0.f) + xv.z;
  float h3 = fmaxf(acc1[3], 0.f) + xv.w;
  hTb[(px0 + 0) * 72 + o_me] = f2bf(h0);
  hTb[(px0 + 1) * 72 + o_me] = f2bf(h1);
  hTb[(px0 + 2) * 72 + o_me] = f2bf(h2);
  hTb[(px0 + 3) * 72 + o_me] = f2bf(h3);
  __syncthreads();

  // ---- conv2 ----
  f32x4 acc2;
  {
    float bo = b2[o_me];
    acc2 = (f32x4){bo, bo, bo, bo};
  }
  const unsigned short* arow2 = hTb + l15 * 72 + (lp << 3);
  const bf16x8* w2f8 = (const bf16x8*)w2p;
#pragma unroll
  for (int s = 0; s < 2; ++s) {
    bf16x8 a = *(const bf16x8*)(arow2 + s * 32);
    bf16x8 bw = w2f8[(s * 4 + wv) * 64 + lane];
    acc2 = __builtin_amdgcn_mfma_f32_16x16x32_bf16(a, bw, acc2, 0, 0, 0);
  }
  *(float4*)(out + (size_t)(b * C_ + o_me) * HW_ + yx0 + px0) =
      make_float4(acc2[0], acc2[1], acc2[2], acc2[3]);
}

extern "C" void kernel_launch(void* const* d_in, const int* in_sizes, int n_in,
                              void* d_out, int out_size, void* d_ws, size_t ws_size,
                              hipStream_t stream) {
  const float* x = (const float*)d_in[0];
  const float* offw = (const float*)d_in[1];
  const float* offb = (const float*)d_in[2];
  const float* dw = (const float*)d_in[3];
  const float* db = (const float*)d_in[4];
  const float* w1 = (const float*)d_in[5];
  const float* b1 = (const float*)d_in[6];
  const float* gamma = (const float*)d_in[7];
  const float* beta = (const float*)d_in[8];
  const float* rmean = (const float*)d_in[9];
  const float* rvar = (const float*)d_in[10];
  const float* w2 = (const float*)d_in[11];
  const float* b2 = (const float*)d_in[12];
  float* out = (float*)d_out;

  float* ws = (float*)d_ws;
  float* p = ws;                        // 8388608 f
  float* off = p + 8388608;             // 2359296 f
  unsigned short* wf2 = (unsigned short*)(off + 2359296);  // 38912 bf16
  unsigned short* offwp = wf2 + 38912;  // 18432 bf16
  unsigned short* w1p = offwp + 18432;  // 4096 bf16
  unsigned short* w2p = w1p + 4096;     // 4096 bf16
  float* b1f = (float*)(w2p + 4096);    // 64 f

  prep_kernel<<<257, 256, 0, stream>>>(dw, offw, w1, b1, gamma, beta, rmean,
                                       rvar, w2, wf2, offwp, w1p, w2p, b1f);
  avgpool_kernel<<<8192, 256, 0, stream>>>(x, p);
  offconv_kernel<<<2048, 256, 0, stream>>>(p, offwp, offb, off);
  deform_kernel<<<8192, 256, 0, stream>>>(p, off, wf2, w1p, w2p, db, b1f, b2,
                                          x, out);
}